// Round 4
// baseline (310.922 us; speedup 1.0000x reference)
//
#include <hip/hip_runtime.h>

#define LDIM 8192
#define HDIM 16
#define DDIM 64
#define NHEADPAIR 64          // N*H
#define ROWSTRIDE 1024        // H*D floats between consecutive l for fixed h
#define KVSZ 4160             // 64*64 KV + 64 ksum
#define EPSF 1e-6f

__device__ __forceinline__ float featmap(float x) {
    // elu(x)+1 : x>0 -> x+1 ; x<=0 -> exp(x)
    return x > 0.0f ? x + 1.0f : __expf(x);
}

// ---------------- Phase 1: partial KV[d][m] and Ksum[d] per (n,h,chunk) -------------
// Register outer-product, one wave per chunk. chunks=128 -> 2048 blocks -> occupancy-
// unconstrained (VGPR ~60 allows 8 waves/SIMD).
__global__ __launch_bounds__(256) void kv_partial_kernel(
    const float* __restrict__ Kp, const float* __restrict__ Vp,
    float* __restrict__ part, int chunks, int rowsPerChunk)
{
    const int nh   = blockIdx.y;            // 0..63
    const int n    = nh >> 4;
    const int h    = nh & 15;
    const int wave = threadIdx.x >> 6;      // 0..3
    const int lane = threadIdx.x & 63;
    const int chunk = blockIdx.x * 4 + wave;
    const int d0 = (lane & 7) * 8;
    const int m0 = (lane >> 3) * 8;

    const size_t base = (((size_t)n * LDIM) * HDIM + h) * DDIM
                      + (size_t)chunk * rowsPerChunk * ROWSTRIDE;
    const float* Kb = Kp + base;
    const float* Vb = Vp + base;

    float acc[8][8];
    float ksum[8];
#pragma unroll
    for (int i = 0; i < 8; ++i) {
        ksum[i] = 0.0f;
#pragma unroll
        for (int j = 0; j < 8; ++j) acc[i][j] = 0.0f;
    }

    // software pipeline: next row's loads in flight during FMA
    float4 ka0 = *(const float4*)(Kb + d0);
    float4 kb0 = *(const float4*)(Kb + d0 + 4);
    float4 va0 = *(const float4*)(Vb + m0);
    float4 vb0 = *(const float4*)(Vb + m0 + 4);

    for (int s = 0; s < rowsPerChunk; ++s) {
        const int sn = (s + 1 < rowsPerChunk) ? s + 1 : s;
        const float* krn = Kb + (size_t)sn * ROWSTRIDE;
        const float* vrn = Vb + (size_t)sn * ROWSTRIDE;
        float4 ka1 = *(const float4*)(krn + d0);
        float4 kb1 = *(const float4*)(krn + d0 + 4);
        float4 va1 = *(const float4*)(vrn + m0);
        float4 vb1 = *(const float4*)(vrn + m0 + 4);

        float kf[8] = { featmap(ka0.x), featmap(ka0.y), featmap(ka0.z), featmap(ka0.w),
                        featmap(kb0.x), featmap(kb0.y), featmap(kb0.z), featmap(kb0.w) };
        float vv[8] = { va0.x, va0.y, va0.z, va0.w, vb0.x, vb0.y, vb0.z, vb0.w };
#pragma unroll
        for (int i = 0; i < 8; ++i) {
            ksum[i] += kf[i];
#pragma unroll
            for (int j = 0; j < 8; ++j) acc[i][j] += kf[i] * vv[j];
        }
        ka0 = ka1; kb0 = kb1; va0 = va1; vb0 = vb1;
    }

    float* p = part + (size_t)(nh * chunks + chunk) * KVSZ;
#pragma unroll
    for (int i = 0; i < 8; ++i) {
        *(float4*)(p + (d0 + i) * 64 + m0) =
            make_float4(acc[i][0], acc[i][1], acc[i][2], acc[i][3]);
        *(float4*)(p + (d0 + i) * 64 + m0 + 4) =
            make_float4(acc[i][4], acc[i][5], acc[i][6], acc[i][7]);
    }
    if (m0 == 0) {
#pragma unroll
        for (int i = 0; i < 8; ++i) p[4096 + d0 + i] = ksum[i];
    }
}

// ---------------- Phase 1b: deterministic parallel reduce of partials ---------------
__global__ __launch_bounds__(256) void kv_reduce_kernel(
    const float* __restrict__ part, float* __restrict__ kvf, int chunks)
{
    const int nh = blockIdx.y;
    const int e  = blockIdx.x * 256 + threadIdx.x;
    if (e >= KVSZ) return;
    float s = 0.0f;
    for (int c = 0; c < chunks; ++c)
        s += part[(size_t)(nh * chunks + c) * KVSZ + e];
    kvf[(size_t)nh * KVSZ + e] = s;
}

// ---------------- Phase 2: out[l][m] = Z * sum_d fm(Q[l,d]) * KV[m][d] ---------------
// Thread tile: 1 row x 32 m (2 lanes share a row -> featmap dup only x2).
__global__ __launch_bounds__(256) void attn_out_kernel(
    const float* __restrict__ Qp, const float* __restrict__ kvf,
    float* __restrict__ out)
{
    __shared__ float Bt[64][68];   // Bt[d][m] = KV[m][d]; 68 keeps b128 rows 16B-aligned
    __shared__ float ks[64];

    const int nh = blockIdx.y;
    const int n  = nh >> 4;
    const int h  = nh & 15;
    const float* kv = kvf + (size_t)nh * KVSZ;

    for (int e = threadIdx.x; e < 4096; e += 256) {
        int m = e >> 6, d = e & 63;
        Bt[d][m] = kv[e];
    }
    if (threadIdx.x < 64) ks[threadIdx.x] = kv[4096 + threadIdx.x];
    __syncthreads();

    const int wave = threadIdx.x >> 6;
    const int lane = threadIdx.x & 63;
    const int mg = lane & 1;            // 2 m-groups
    const int lg = lane >> 1;           // 32 rows per wave
    const int m0 = mg * 32;
    const int l0 = blockIdx.x * 128 + wave * 32 + lg;   // 1 row per thread

    const float* Qb = Qp + (((size_t)n * LDIM) * HDIM + h) * DDIM
                    + (size_t)l0 * ROWSTRIDE;

    float acc[32];
    float zacc = 0.0f;
#pragma unroll
    for (int j = 0; j < 32; ++j) acc[j] = 0.0f;

#pragma unroll
    for (int c8 = 0; c8 < 8; ++c8) {
        const int dd = c8 * 8;
        float4 a = *(const float4*)(Qb + dd);
        float4 b = *(const float4*)(Qb + dd + 4);
        float qf[8] = { featmap(a.x), featmap(a.y), featmap(a.z), featmap(a.w),
                        featmap(b.x), featmap(b.y), featmap(b.z), featmap(b.w) };
#pragma unroll
        for (int j = 0; j < 8; ++j) {
            const float q = qf[j];
            zacc += q * ks[dd + j];
#pragma unroll
            for (int qd = 0; qd < 8; ++qd) {
                float4 bb = *(const float4*)(&Bt[dd + j][m0 + qd * 4]);
                acc[qd * 4 + 0] += q * bb.x;
                acc[qd * 4 + 1] += q * bb.y;
                acc[qd * 4 + 2] += q * bb.z;
                acc[qd * 4 + 3] += q * bb.w;
            }
        }
    }

    const float z = 1.0f / (zacc + EPSF);
    float* orow = out + (((size_t)n * LDIM + l0) * HDIM + h) * DDIM + m0;
#pragma unroll
    for (int qd = 0; qd < 8; ++qd) {
        *(float4*)(orow + qd * 4) =
            make_float4(acc[qd * 4 + 0] * z, acc[qd * 4 + 1] * z,
                        acc[qd * 4 + 2] * z, acc[qd * 4 + 3] * z);
    }
}

extern "C" void kernel_launch(void* const* d_in, const int* in_sizes, int n_in,
                              void* d_out, int out_size, void* d_ws, size_t ws_size,
                              hipStream_t stream) {
    const float* Q = (const float*)d_in[0];
    const float* K = (const float*)d_in[1];
    const float* V = (const float*)d_in[2];
    float* out = (float*)d_out;
    float* ws  = (float*)d_ws;

    // pick chunk count (per head-pair) that fits the workspace
    int chunks = 128;
    while (chunks > 4 &&
           ((size_t)NHEADPAIR * chunks + NHEADPAIR) * KVSZ * sizeof(float) > ws_size)
        chunks >>= 1;
    const int rowsPerChunk = LDIM / chunks;

    float* part = ws;
    float* kvf  = ws + (size_t)NHEADPAIR * chunks * KVSZ;

    dim3 g1(chunks / 4, NHEADPAIR);
    kv_partial_kernel<<<g1, 256, 0, stream>>>(K, V, part, chunks, rowsPerChunk);
    dim3 gr((KVSZ + 255) / 256, NHEADPAIR);
    kv_reduce_kernel<<<gr, 256, 0, stream>>>(part, kvf, chunks);
    dim3 g2(LDIM / 128, NHEADPAIR);
    attn_out_kernel<<<g2, 256, 0, stream>>>(Q, kvf, out);
}